// Round 4
// baseline (2836.902 us; speedup 1.0000x reference)
//
#include <hip/hip_runtime.h>
#include <stdint.h>

#define B_ 256
#define T_ 512
#define D_ 128
#define H_ 256

typedef __attribute__((ext_vector_type(8))) _Float16 half8;
typedef __attribute__((ext_vector_type(4))) float f32x4;

// ws layout (bytes)
#define WS_FLAG 0        // [16 groups][16 slices] epoch flags, 64 B apart (16 KB)
#define WS_PART 16384    // 16*256 floats fc partials (16 KB)
#define WS_H0   65536    // [2][256][256] f16 layer0 h double buffer
#define WS_H1   327680   // [2][256][256] f16 layer1 h double buffer

__device__ __forceinline__ float fast_sig(float x) {
    return 1.0f / (1.0f + __expf(-x));
}
__device__ __forceinline__ float fast_tanh(float x) {
    float xc = fminf(fmaxf(x, -30.0f), 30.0f);
    float e = __expf(-2.0f * xc);
    return (1.0f - e) / (1.0f + e);
}
__device__ __forceinline__ half8 cvt8(const float* p) {
    const f32x4* q = (const f32x4*)p;
    f32x4 a = q[0], b = q[1];
    half8 r;
    r[0] = (_Float16)a[0]; r[1] = (_Float16)a[1];
    r[2] = (_Float16)a[2]; r[3] = (_Float16)a[3];
    r[4] = (_Float16)b[0]; r[5] = (_Float16)b[1];
    r[6] = (_Float16)b[2]; r[7] = (_Float16)b[3];
    return r;
}
__device__ __forceinline__ half8 cvt8v(f32x4 a, f32x4 b) {
    half8 r;
    r[0] = (_Float16)a[0]; r[1] = (_Float16)a[1];
    r[2] = (_Float16)a[2]; r[3] = (_Float16)a[3];
    r[4] = (_Float16)b[0]; r[5] = (_Float16)b[1];
    r[6] = (_Float16)b[2]; r[7] = (_Float16)b[3];
    return r;
}

// ---- MALL-coherent primitives (sc0 sc1 = bypass L1+L2, device coherence pt) ----
__device__ __forceinline__ void load8_mall_nowait(const _Float16* p, half8* f) {
    asm volatile(
        "global_load_dwordx4 %0, %8, off sc0 sc1\n\t"
        "global_load_dwordx4 %1, %8, off offset:64 sc0 sc1\n\t"
        "global_load_dwordx4 %2, %8, off offset:128 sc0 sc1\n\t"
        "global_load_dwordx4 %3, %8, off offset:192 sc0 sc1\n\t"
        "global_load_dwordx4 %4, %8, off offset:256 sc0 sc1\n\t"
        "global_load_dwordx4 %5, %8, off offset:320 sc0 sc1\n\t"
        "global_load_dwordx4 %6, %8, off offset:384 sc0 sc1\n\t"
        "global_load_dwordx4 %7, %8, off offset:448 sc0 sc1"
        : "=&v"(f[0]), "=&v"(f[1]), "=&v"(f[2]), "=&v"(f[3]),
          "=&v"(f[4]), "=&v"(f[5]), "=&v"(f[6]), "=&v"(f[7])
        : "v"(p) : "memory");
}
__device__ __forceinline__ void load8_mall_wait(const _Float16* p, half8* f) {
    asm volatile(
        "global_load_dwordx4 %0, %8, off sc0 sc1\n\t"
        "global_load_dwordx4 %1, %8, off offset:64 sc0 sc1\n\t"
        "global_load_dwordx4 %2, %8, off offset:128 sc0 sc1\n\t"
        "global_load_dwordx4 %3, %8, off offset:192 sc0 sc1\n\t"
        "global_load_dwordx4 %4, %8, off offset:256 sc0 sc1\n\t"
        "global_load_dwordx4 %5, %8, off offset:320 sc0 sc1\n\t"
        "global_load_dwordx4 %6, %8, off offset:384 sc0 sc1\n\t"
        "global_load_dwordx4 %7, %8, off offset:448 sc0 sc1\n\t"
        "s_waitcnt vmcnt(0)"
        : "=&v"(f[0]), "=&v"(f[1]), "=&v"(f[2]), "=&v"(f[3]),
          "=&v"(f[4]), "=&v"(f[5]), "=&v"(f[6]), "=&v"(f[7])
        : "v"(p) : "memory");
}
__device__ __forceinline__ void store_h_mall(_Float16* p, float v) {
    union { _Float16 h; short s; } u;
    u.h = (_Float16)v;
    int vi = u.s;
    asm volatile("global_store_short %0, %1, off sc0 sc1" :: "v"(p), "v"(vi) : "memory");
}
__device__ __forceinline__ void store_flag_mall(int* p, int v) {
    asm volatile("global_store_dword %0, %1, off sc0 sc1" :: "v"(p), "v"(v) : "memory");
}
__device__ __forceinline__ int load_flag_mall(const int* p) {
    int v;
    asm volatile("global_load_dword %0, %1, off sc0 sc1\n\ts_waitcnt vmcnt(0)"
                 : "=&v"(v) : "v"(p) : "memory");
    return v;
}

__global__ void lstm_init(char* ws) {
    int* f = (int*)(ws + WS_FLAG);
    for (int i = threadIdx.x; i < 4096; i += 256) f[i] = 0;
}

// grid 256 wgs x 256 thr. wg = (batch group g = blk&15) x (hidden slice sl = blk>>4)
// wave w = gate (i,f,g,o); weights pinned in regs as f16 MFMA B-frags.
// Layer-pipelined: iter u does layer0 step u (u<T) and layer1 step u-1 (u>=1).
// Cross-wg h + epoch flags live at MALL via sc0 sc1 (G16-safe, placement-free).
// Barrier: 16 spread flag lines (no RMW, no hot line); parallel 16-lane poll.
__global__ __launch_bounds__(256, 1) void lstm_main(
    const float* __restrict__ x, const int* __restrict__ mask,
    const float* __restrict__ Wih0, const float* __restrict__ Whh0,
    const float* __restrict__ bih0, const float* __restrict__ bhh0,
    const float* __restrict__ Wih1, const float* __restrict__ Whh1,
    const float* __restrict__ bih1, const float* __restrict__ bhh1,
    const float* __restrict__ fcw, char* __restrict__ ws)
{
    const int tid  = threadIdx.x;
    const int blk  = blockIdx.x;
    const int g    = blk & 15;    // batch group
    const int sl   = blk >> 4;    // hidden slice
    const int b0   = g * 16;
    const int j0   = sl * 16;
    const int w    = tid >> 6;
    const int lane = tid & 63;
    const int row  = lane & 15;
    const int quad = lane >> 4;
    const int kb   = quad * 8;

    int*      flags    = (int*)(ws + WS_FLAG) + g * 256;  // 16 lines, 16 ints apart
    float*    partials = (float*)(ws + WS_PART);
    _Float16* h0buf    = (_Float16*)(ws + WS_H0);
    _Float16* h1buf    = (_Float16*)(ws + WS_H1);

    __shared__ float gbuf[2048];

    // ---- pin weights in registers (f16 B-frags), n = gate row ----
    const int n = w * H_ + j0 + row;
    half8 wA[12], wB[16];
#pragma unroll
    for (int kt = 0; kt < 4; ++kt) wA[kt]     = cvt8(&Wih0[(size_t)n * D_ + kt * 32 + kb]);
#pragma unroll
    for (int kt = 0; kt < 8; ++kt) wA[4 + kt] = cvt8(&Whh0[(size_t)n * H_ + kt * 32 + kb]);
#pragma unroll
    for (int kt = 0; kt < 8; ++kt) wB[kt]     = cvt8(&Wih1[(size_t)n * H_ + kt * 32 + kb]);
#pragma unroll
    for (int kt = 0; kt < 8; ++kt) wB[8 + kt] = cvt8(&Whh1[(size_t)n * H_ + kt * 32 + kb]);
    const float biasA = bih0[n] + bhh0[n];
    const float biasB = bih1[n] + bhh1[n];

    const int bb    = tid >> 4;
    const int jj    = tid & 15;
    const int bglob = b0 + bb;

    int len = 0;
    {
        const int* mrow = mask + (size_t)bglob * T_ + jj * 32;
#pragma unroll
        for (int q = 0; q < 32; ++q) len += mrow[q];
#pragma unroll
        for (int o = 1; o < 16; o <<= 1) len += __shfl_xor(len, o, 16);
    }

    float c0 = 0.f, c1 = 0.f, hsave = 0.f;

    // x fragments for step 0
    const float* xrow = x + (size_t)(b0 + row) * T_ * D_ + kb;
    f32x4 xr[8];
    {
        const f32x4* q = (const f32x4*)xrow;
#pragma unroll
        for (int kt = 0; kt < 4; ++kt) { xr[2 * kt] = q[kt * 8]; xr[2 * kt + 1] = q[kt * 8 + 1]; }
    }
    f32x4 xacc = {0.f, 0.f, 0.f, 0.f};
#pragma unroll
    for (int kt = 0; kt < 4; ++kt)
        xacc = __builtin_amdgcn_mfma_f32_16x16x32_f16(cvt8v(xr[2 * kt], xr[2 * kt + 1]), wA[kt], xacc, 0, 0, 0);

    for (int u = 0; u <= T_; ++u) {
        // ---- prefetch x for step u+1 (plain loads; complete under h-load wait) ----
        {
            const int tn = (u + 1 < T_) ? (u + 1) : (T_ - 1);
            const f32x4* q = (const f32x4*)(xrow + (size_t)tn * D_);
#pragma unroll
            for (int kt = 0; kt < 4; ++kt) { xr[2 * kt] = q[kt * 8]; xr[2 * kt + 1] = q[kt * 8 + 1]; }
        }

        f32x4 acc0 = xacc;                 // layer0 x-part (valid when u<T)
        f32x4 acc1 = {0.f, 0.f, 0.f, 0.f};

        if (u >= 1) {
            half8 hg[8];  // h1_{u-2} frags
            if (u >= 2)
                load8_mall_nowait(h1buf + ((size_t)((u - 2) & 1) * B_ + (b0 + row)) * H_ + kb, hg);
            half8 hf[8];  // h0_{u-1} frags
            load8_mall_wait(h0buf + ((size_t)((u - 1) & 1) * B_ + (b0 + row)) * H_ + kb, hf);
#pragma unroll
            for (int kt = 0; kt < 8; ++kt) {
                if (u < T_) acc0 = __builtin_amdgcn_mfma_f32_16x16x32_f16(hf[kt], wA[4 + kt], acc0, 0, 0, 0);
                acc1 = __builtin_amdgcn_mfma_f32_16x16x32_f16(hf[kt], wB[kt], acc1, 0, 0, 0);
            }
            if (u >= 2) {
#pragma unroll
                for (int kt = 0; kt < 8; ++kt)
                    acc1 = __builtin_amdgcn_mfma_f32_16x16x32_f16(hg[kt], wB[8 + kt], acc1, 0, 0, 0);
            }
        }

        // gates -> LDS (+bias). D-frag: value r is [m=quad*4+r][n=row]
        if (u < T_) {
#pragma unroll
            for (int r = 0; r < 4; ++r)
                gbuf[w * 256 + (quad * 4 + r) * 16 + row] = acc0[r] + biasA;
        }
        if (u >= 1) {
#pragma unroll
            for (int r = 0; r < 4; ++r)
                gbuf[1024 + w * 256 + (quad * 4 + r) * 16 + row] = acc1[r] + biasB;
        }
        __syncthreads();

        const int idx = bb * 16 + jj;
        if (u < T_) {
            float gi = fast_sig(gbuf[idx]);
            float gf = fast_sig(gbuf[256 + idx]);
            float gg = fast_tanh(gbuf[512 + idx]);
            float go = fast_sig(gbuf[768 + idx]);
            c0 = gf * c0 + gi * gg;
            float h0v = go * fast_tanh(c0);
            store_h_mall(&h0buf[((size_t)(u & 1) * B_ + bglob) * H_ + j0 + jj], h0v);
        }
        if (u >= 1) {
            float gi = fast_sig(gbuf[1024 + idx]);
            float gf = fast_sig(gbuf[1024 + 256 + idx]);
            float gg = fast_tanh(gbuf[1024 + 512 + idx]);
            float go = fast_sig(gbuf[1024 + 768 + idx]);
            c1 = gf * c1 + gi * gg;
            float h1v = go * fast_tanh(c1);
            store_h_mall(&h1buf[((size_t)((u - 1) & 1) * B_ + bglob) * H_ + j0 + jj], h1v);
            if (u == len) hsave = h1v;
        }

        // xacc for step u+1 (x loads issued at top; long complete)
        xacc[0] = 0.f; xacc[1] = 0.f; xacc[2] = 0.f; xacc[3] = 0.f;
#pragma unroll
        for (int kt = 0; kt < 4; ++kt)
            xacc = __builtin_amdgcn_mfma_f32_16x16x32_f16(cvt8v(xr[2 * kt], xr[2 * kt + 1]), wA[kt], xacc, 0, 0, 0);

        // ---- group barrier: spread flag lines at MALL (one per step) ----
        if (u < T_) {
            asm volatile("s_waitcnt vmcnt(0)" ::: "memory");  // h stores acked at MALL
            __syncthreads();                                   // all waves drained
            if (tid == 0) store_flag_mall(&flags[sl * 16], u + 1);  // arrive (fire)
            // all waves poll: lanes map onto the 16 flag lines in parallel
            const int* fp = &flags[(lane & 15) * 16];
            const int target = u + 1;
            int guard = 0;
            while (true) {
                int v = load_flag_mall(fp);
                if (__all(v >= target)) break;
                if (++guard > (1 << 15)) break;  // bounded: fail loud, never hang
            }
        }
    }

    float part = hsave * fcw[j0 + jj];
#pragma unroll
    for (int o = 1; o < 16; o <<= 1) part += __shfl_xor(part, o, 16);
    if (jj == 0) partials[sl * B_ + bglob] = part;
}

__global__ void lstm_fc(const float* __restrict__ fcb, const char* __restrict__ ws,
                        float* __restrict__ out) {
    const int b = threadIdx.x;
    const float* partials = (const float*)(ws + WS_PART);
    float s = fcb[0];
#pragma unroll
    for (int sl = 0; sl < 16; ++sl) s += partials[sl * B_ + b];
    out[b] = s;
}

extern "C" void kernel_launch(void* const* d_in, const int* in_sizes, int n_in,
                              void* d_out, int out_size, void* d_ws, size_t ws_size,
                              hipStream_t stream) {
    const float* xx    = (const float*)d_in[0];
    const int*   mask  = (const int*)d_in[1];
    const float* Wih0  = (const float*)d_in[2];
    const float* Whh0  = (const float*)d_in[3];
    const float* bih0  = (const float*)d_in[4];
    const float* bhh0  = (const float*)d_in[5];
    const float* Wih1  = (const float*)d_in[6];
    const float* Whh1  = (const float*)d_in[7];
    const float* bih1  = (const float*)d_in[8];
    const float* bhh1  = (const float*)d_in[9];
    const float* fcw   = (const float*)d_in[10];
    const float* fcb   = (const float*)d_in[11];

    lstm_init<<<dim3(1), dim3(256), 0, stream>>>((char*)d_ws);
    lstm_main<<<dim3(256), dim3(256), 0, stream>>>(
        xx, mask, Wih0, Whh0, bih0, bhh0, Wih1, Whh1, bih1, bhh1, fcw, (char*)d_ws);
    lstm_fc<<<dim3(1), dim3(256), 0, stream>>>(fcb, (const char*)d_ws, (float*)d_out);
}